// Round 7
// baseline (499.266 us; speedup 1.0000x reference)
//
#include <hip/hip_runtime.h>

#define S_LEN    2048
#define DK       64
#define N_BH     32
#define ROWS     16
#define NTHREADS 512

typedef float          f32x4  __attribute__((ext_vector_type(4)));
typedef int            i32x4  __attribute__((ext_vector_type(4)));
typedef short          bf16x8 __attribute__((ext_vector_type(8)));
typedef unsigned short u16x8  __attribute__((ext_vector_type(8)));
typedef unsigned int   u32x4  __attribute__((ext_vector_type(4)));

__device__ __forceinline__ unsigned short f2bf(float f) {
    unsigned u = __builtin_bit_cast(unsigned, f);
    u += 0x7fffu + ((u >> 16) & 1u);
    return (unsigned short)(u >> 16);
}
__device__ __forceinline__ float bf2f(unsigned short h) {
    unsigned u = ((unsigned)h) << 16;
    return __builtin_bit_cast(float, u);
}
__device__ __forceinline__ unsigned pack_bf2(float a, float b) {
    return (unsigned)f2bf(a) | ((unsigned)f2bf(b) << 16);
}

// ---------------- prep kernels (bf16 pre-conversion into d_ws) ----------------
__global__ void prep_qcast(const float* __restrict__ q, unsigned short* __restrict__ Qb) {
    const long i = ((long)blockIdx.x * 256 + threadIdx.x) * 8;
    f32x4 a = *(const f32x4*)(q + i);
    f32x4 b = *(const f32x4*)(q + i + 4);
    u16x8 o;
    o[0]=f2bf(a.x); o[1]=f2bf(a.y); o[2]=f2bf(a.z); o[3]=f2bf(a.w);
    o[4]=f2bf(b.x); o[5]=f2bf(b.y); o[6]=f2bf(b.z); o[7]=f2bf(b.w);
    *(u16x8*)(Qb + i) = o;
}

// k[bh][64][2048] (f32) -> Kb[bh][2048][64] (bf16)
__global__ void prep_k(const float* __restrict__ k, unsigned short* __restrict__ Kb) {
    __shared__ float t[64][65];
    const int bh = blockIdx.x >> 5, s0 = (blockIdx.x & 31) << 6;
    const int tx = threadIdx.x;
    const float* kb = k + (long)bh * 64 * S_LEN;
    #pragma unroll
    for (int i = 0; i < 16; ++i) {
        const int d = (i << 2) + (tx >> 6), s = tx & 63;
        t[d][s] = kb[(long)d * S_LEN + s0 + s];
    }
    __syncthreads();
    #pragma unroll
    for (int i = 0; i < 16; ++i) {
        const int s = (i << 2) + (tx >> 6), d = tx & 63;
        Kb[((long)bh * S_LEN + s0 + s) * DK + d] = f2bf(t[d][s]);
    }
}

// v[bh][2048][64] (f32) -> Vb[bh][64][2048] (bf16)
__global__ void prep_v(const float* __restrict__ v, unsigned short* __restrict__ Vb) {
    __shared__ float t[64][65];
    const int bh = blockIdx.x >> 5, s0 = (blockIdx.x & 31) << 6;
    const int tx = threadIdx.x;
    #pragma unroll
    for (int i = 0; i < 16; ++i) {
        const int s = (i << 2) + (tx >> 6), d = tx & 63;
        t[s][d] = v[((long)bh * S_LEN + s0 + s) * DK + d];
    }
    __syncthreads();
    #pragma unroll
    for (int i = 0; i < 16; ++i) {
        const int d = (i << 2) + (tx >> 6), s = tx & 63;
        Vb[((long)bh * DK + d) * S_LEN + s0 + s] = f2bf(t[s][d]);
    }
}

// ---------------------------- main attention kernel ----------------------------
// Fully-fused per-32-col chunk: QK^T -> exp -> shfl to row-contiguous af ->
// mask (32B/lane coalesced) -> rsum + PV MFMAs. attn streamed in pass B.
template <bool WS>
__global__ __launch_bounds__(NTHREADS, 4)
void sdpa_main(const float* __restrict__ q, const float* __restrict__ k,
               const float* __restrict__ v, const int* __restrict__ mask,
               const unsigned short* __restrict__ Qb,
               const unsigned short* __restrict__ Kb,
               const unsigned short* __restrict__ Vb,
               float* __restrict__ ctx, float* __restrict__ attn)
{
    __shared__ float rowsum[ROWS];
    __shared__ float ctxlds[ROWS * DK];

    const int bid  = blockIdx.x;
    const int bh   = bid & (N_BH - 1);         // head-minor for K/V L2 locality
    const int qt   = bid >> 5;
    const int tid  = threadIdx.x;
    const int wave = tid >> 6;
    const int lane = tid & 63;
    const int m    = lane & 15;
    const int g    = lane >> 4;
    const long rowbase = (long)bh * S_LEN + qt * ROWS;

    if (tid < ROWS) rowsum[tid] = 0.0f;
    for (int i = tid; i < ROWS * DK; i += NTHREADS) ctxlds[i] = 0.0f;
    __syncthreads();

    // Q fragment (B operand): Q[col=m][k = ks*32 + g*8 + j]
    bf16x8 qfrag[2];
    if (WS) {
        const unsigned short* qp = Qb + (rowbase + m) * DK;
        qfrag[0] = *(const bf16x8*)(qp + g * 8);
        qfrag[1] = *(const bf16x8*)(qp + 32 + g * 8);
    } else {
        const float* qp = q + (rowbase + m) * DK;
        #pragma unroll
        for (int ks = 0; ks < 2; ++ks) {
            const float* p = qp + ks * 32 + g * 8;
            f32x4 x0 = *(const f32x4*)p, x1 = *(const f32x4*)(p + 4);
            qfrag[ks][0]=(short)f2bf(x0.x); qfrag[ks][1]=(short)f2bf(x0.y);
            qfrag[ks][2]=(short)f2bf(x0.z); qfrag[ks][3]=(short)f2bf(x0.w);
            qfrag[ks][4]=(short)f2bf(x1.x); qfrag[ks][5]=(short)f2bf(x1.y);
            qfrag[ks][6]=(short)f2bf(x1.z); qfrag[ks][7]=(short)f2bf(x1.w);
        }
    }

    const int tw   = wave << 8;                // this wave's 256-col slice
    const int srcA = ((g & 1) << 5) + m;
    const int srcB = srcA + 16;
    const int hi   = g >> 1;
    const int* mrow = mask + (rowbase + m) * (long)S_LEN;

    u32x4 AF[8];                               // masked e, af layout (row m, 8 cols)
    f32x4 cacc0 = {0,0,0,0}, cacc1 = {0,0,0,0}, cacc2 = {0,0,0,0}, cacc3 = {0,0,0,0};
    float rsum = 0.0f;

    #pragma unroll
    for (int kt = 0; kt < 8; ++kt) {
        // ---- QK^T for ct = 2kt (even) and 2kt+1 (odd) ----
        unsigned pk0e, pk1e, pk0o, pk1o;
        #pragma unroll
        for (int h = 0; h < 2; ++h) {
            const int t0 = tw + ((2 * kt + h) << 4);
            const int tk = t0 + m;             // A operand: K row (t dim)
            f32x4 acc = {0.f, 0.f, 0.f, 0.f};
            #pragma unroll
            for (int ks = 0; ks < 2; ++ks) {
                bf16x8 kfrag;
                if (WS) {
                    kfrag = *(const bf16x8*)(Kb + ((long)bh * S_LEN + tk) * DK + ks * 32 + g * 8);
                } else {
                    const float* kp = k + (long)bh * DK * S_LEN + (long)(ks * 32 + g * 8) * S_LEN + tk;
                    #pragma unroll
                    for (int j = 0; j < 8; ++j) kfrag[j] = (short)f2bf(kp[(long)j * S_LEN]);
                }
                acc = __builtin_amdgcn_mfma_f32_16x16x32_bf16(kfrag, qfrag[ks], acc, 0, 0, 0);
            }
            // acc[i] = S[q=m][t = t0 + 4g + i]
            const float e0 = __expf(acc[0] * 0.125f);
            const float e1 = __expf(acc[1] * 0.125f);
            const float e2 = __expf(acc[2] * 0.125f);
            const float e3 = __expf(acc[3] * 0.125f);
            if (h == 0) { pk0e = pack_bf2(e0, e1); pk1e = pack_bf2(e2, e3); }
            else        { pk0o = pack_bf2(e0, e1); pk1o = pack_bf2(e2, e3); }
        }
        // ---- shfl: af = P[row m][cols tb..tb+7], tb = tw + kt*32 + g*8 ----
        const unsigned a0e = (unsigned)__shfl((int)pk0e, srcA);
        const unsigned a0o = (unsigned)__shfl((int)pk0o, srcA);
        const unsigned a1e = (unsigned)__shfl((int)pk1e, srcA);
        const unsigned a1o = (unsigned)__shfl((int)pk1o, srcA);
        const unsigned a2e = (unsigned)__shfl((int)pk0e, srcB);
        const unsigned a2o = (unsigned)__shfl((int)pk0o, srcB);
        const unsigned a3e = (unsigned)__shfl((int)pk1e, srcB);
        const unsigned a3o = (unsigned)__shfl((int)pk1o, srcB);
        u32x4 wv = { hi ? a0o : a0e, hi ? a1o : a1e,
                     hi ? a2o : a2e, hi ? a3o : a3e };
        // ---- mask: 32B/lane contiguous (4 lanes/row -> 128B/row) ----
        const int tb = tw + (kt << 5) + (g << 3);
        const i32x4 mk0 = *(const i32x4*)(mrow + tb);
        const i32x4 mk1 = *(const i32x4*)(mrow + tb + 4);
        if (mk0.x) wv.x &= 0xFFFF0000u;  if (mk0.y) wv.x &= 0x0000FFFFu;
        if (mk0.z) wv.y &= 0xFFFF0000u;  if (mk0.w) wv.y &= 0x0000FFFFu;
        if (mk1.x) wv.z &= 0xFFFF0000u;  if (mk1.y) wv.z &= 0x0000FFFFu;
        if (mk1.z) wv.w &= 0xFFFF0000u;  if (mk1.w) wv.w &= 0x0000FFFFu;
        AF[kt] = wv;
        rsum += ((bf2f((unsigned short)(wv.x & 0xFFFF)) + bf2f((unsigned short)(wv.x >> 16)))
               + (bf2f((unsigned short)(wv.y & 0xFFFF)) + bf2f((unsigned short)(wv.y >> 16))))
              + ((bf2f((unsigned short)(wv.z & 0xFFFF)) + bf2f((unsigned short)(wv.z >> 16)))
               + (bf2f((unsigned short)(wv.w & 0xFFFF)) + bf2f((unsigned short)(wv.w >> 16))));
        // ---- PV MFMAs: A = af (masked), B = V[col=dt*16+m][k=tb+j] ----
        const bf16x8 af = __builtin_bit_cast(bf16x8, wv);
        #pragma unroll
        for (int dt = 0; dt < 4; ++dt) {
            bf16x8 bfv;
            if (WS) {
                bfv = *(const bf16x8*)(Vb + ((long)bh * DK + dt * 16 + m) * S_LEN + tb);
            } else {
                const float* vp = v + ((long)bh * S_LEN + tb) * DK + dt * 16 + m;
                #pragma unroll
                for (int j = 0; j < 8; ++j) bfv[j] = (short)f2bf(vp[j * DK]);
            }
            if      (dt == 0) cacc0 = __builtin_amdgcn_mfma_f32_16x16x32_bf16(af, bfv, cacc0, 0, 0, 0);
            else if (dt == 1) cacc1 = __builtin_amdgcn_mfma_f32_16x16x32_bf16(af, bfv, cacc1, 0, 0, 0);
            else if (dt == 2) cacc2 = __builtin_amdgcn_mfma_f32_16x16x32_bf16(af, bfv, cacc2, 0, 0, 0);
            else              cacc3 = __builtin_amdgcn_mfma_f32_16x16x32_bf16(af, bfv, cacc3, 0, 0, 0);
        }
    }

    // ---- reductions: rowsum + ctx partials ----
    rsum += __shfl_xor(rsum, 16);
    rsum += __shfl_xor(rsum, 32);              // lanes sharing m agree
    if (lane < 16) atomicAdd(&rowsum[lane], rsum);
    #pragma unroll
    for (int i = 0; i < 4; ++i) {
        atomicAdd(&ctxlds[(4 * g + i) * DK +  0 + m], cacc0[i]);
        atomicAdd(&ctxlds[(4 * g + i) * DK + 16 + m], cacc1[i]);
        atomicAdd(&ctxlds[(4 * g + i) * DK + 32 + m], cacc2[i]);
        atomicAdd(&ctxlds[(4 * g + i) * DK + 48 + m], cacc3[i]);
    }
    __syncthreads();

    // ---- pass B: stream attn = AF * rinv (nontemporal, 128B/row segments) ----
    {
        const float rinv = 1.0f / rowsum[m];
        float* aout = attn + (rowbase + m) * (long)S_LEN;
        #pragma unroll
        for (int kt = 0; kt < 8; ++kt) {
            const u32x4 wv = AF[kt];
            const int tb = tw + (kt << 5) + (g << 3);
            f32x4 o0 = { bf2f((unsigned short)(wv.x & 0xFFFF)) * rinv,
                         bf2f((unsigned short)(wv.x >> 16))    * rinv,
                         bf2f((unsigned short)(wv.y & 0xFFFF)) * rinv,
                         bf2f((unsigned short)(wv.y >> 16))    * rinv };
            f32x4 o1 = { bf2f((unsigned short)(wv.z & 0xFFFF)) * rinv,
                         bf2f((unsigned short)(wv.z >> 16))    * rinv,
                         bf2f((unsigned short)(wv.w & 0xFFFF)) * rinv,
                         bf2f((unsigned short)(wv.w >> 16))    * rinv };
            __builtin_nontemporal_store(o0, (f32x4*)(aout + tb));
            __builtin_nontemporal_store(o1, (f32x4*)(aout + tb + 4));
        }
    }

    // ---- ctx epilogue ----
    #pragma unroll
    for (int i = tid; i < ROWS * DK; i += NTHREADS) {
        const int rr = i >> 6, dd = i & 63;
        ctx[(rowbase + rr) * DK + dd] = ctxlds[i] / rowsum[rr];
    }
}

extern "C" void kernel_launch(void* const* d_in, const int* in_sizes, int n_in,
                              void* d_out, int out_size, void* d_ws, size_t ws_size,
                              hipStream_t stream)
{
    const float* q    = (const float*)d_in[0];
    const float* k    = (const float*)d_in[1];
    const float* v    = (const float*)d_in[2];
    const int*   mask = (const int*)d_in[3];

    float* ctx  = (float*)d_out;
    float* attn = ctx + (size_t)N_BH * S_LEN * DK;

    const size_t nel = (size_t)N_BH * S_LEN * DK;
    const bool use_ws = ws_size >= nel * 3 * sizeof(unsigned short);
    unsigned short* Qb = (unsigned short*)d_ws;
    unsigned short* Kb = Qb + nel;
    unsigned short* Vb = Kb + nel;

    const int nblocks = N_BH * (S_LEN / ROWS);                 // 4096

    if (use_ws) {
        prep_qcast<<<(int)(nel / (256 * 8)), 256, 0, stream>>>(q, Qb);
        prep_k<<<N_BH * (S_LEN / 64), 256, 0, stream>>>(k, Kb);
        prep_v<<<N_BH * (S_LEN / 64), 256, 0, stream>>>(v, Vb);
        sdpa_main<true><<<nblocks, NTHREADS, 0, stream>>>(q, k, v, mask, Qb, Kb, Vb, ctx, attn);
    } else {
        sdpa_main<false><<<nblocks, NTHREADS, 0, stream>>>(q, k, v, mask,
                                                           nullptr, nullptr, nullptr, ctx, attn);
    }
}

// Round 8
// 475.907 us; speedup vs baseline: 1.0491x; 1.0491x over previous
//
#include <hip/hip_runtime.h>

#define S_LEN    2048
#define DK       64
#define N_BH     32
#define ROWS     16
#define NTHREADS 512

typedef float          f32x4  __attribute__((ext_vector_type(4)));
typedef int            i32x4  __attribute__((ext_vector_type(4)));
typedef short          bf16x8 __attribute__((ext_vector_type(8)));
typedef unsigned short u16x8  __attribute__((ext_vector_type(8)));
typedef unsigned int   u32x4  __attribute__((ext_vector_type(4)));

__device__ __forceinline__ unsigned short f2bf(float f) {
    unsigned u = __builtin_bit_cast(unsigned, f);
    u += 0x7fffu + ((u >> 16) & 1u);
    return (unsigned short)(u >> 16);
}
__device__ __forceinline__ float bf2f(unsigned short h) {
    unsigned u = ((unsigned)h) << 16;
    return __builtin_bit_cast(float, u);
}
__device__ __forceinline__ unsigned pack_bf2(float a, float b) {
    return (unsigned)f2bf(a) | ((unsigned)f2bf(b) << 16);
}

// ---------------- prep kernels (bf16 pre-conversion into d_ws) ----------------
__global__ void prep_qcast(const float* __restrict__ q, unsigned short* __restrict__ Qb) {
    const long i = ((long)blockIdx.x * 256 + threadIdx.x) * 8;
    f32x4 a = *(const f32x4*)(q + i);
    f32x4 b = *(const f32x4*)(q + i + 4);
    u16x8 o;
    o[0]=f2bf(a.x); o[1]=f2bf(a.y); o[2]=f2bf(a.z); o[3]=f2bf(a.w);
    o[4]=f2bf(b.x); o[5]=f2bf(b.y); o[6]=f2bf(b.z); o[7]=f2bf(b.w);
    *(u16x8*)(Qb + i) = o;
}

// k[bh][64][2048] (f32) -> Kb[bh][2048][64] (bf16)
__global__ void prep_k(const float* __restrict__ k, unsigned short* __restrict__ Kb) {
    __shared__ float t[64][65];
    const int bh = blockIdx.x >> 5, s0 = (blockIdx.x & 31) << 6;
    const int tx = threadIdx.x;
    const float* kb = k + (long)bh * 64 * S_LEN;
    #pragma unroll
    for (int i = 0; i < 16; ++i) {
        const int d = (i << 2) + (tx >> 6), s = tx & 63;
        t[d][s] = kb[(long)d * S_LEN + s0 + s];
    }
    __syncthreads();
    #pragma unroll
    for (int i = 0; i < 16; ++i) {
        const int s = (i << 2) + (tx >> 6), d = tx & 63;
        Kb[((long)bh * S_LEN + s0 + s) * DK + d] = f2bf(t[d][s]);
    }
}

// v[bh][2048][64] (f32) -> Vb[bh][64][2048] (bf16)
__global__ void prep_v(const float* __restrict__ v, unsigned short* __restrict__ Vb) {
    __shared__ float t[64][65];
    const int bh = blockIdx.x >> 5, s0 = (blockIdx.x & 31) << 6;
    const int tx = threadIdx.x;
    #pragma unroll
    for (int i = 0; i < 16; ++i) {
        const int s = (i << 2) + (tx >> 6), d = tx & 63;
        t[s][d] = v[((long)bh * S_LEN + s0 + s) * DK + d];
    }
    __syncthreads();
    #pragma unroll
    for (int i = 0; i < 16; ++i) {
        const int d = (i << 2) + (tx >> 6), s = tx & 63;
        Vb[((long)bh * DK + d) * S_LEN + s0 + s] = f2bf(t[s][d]);
    }
}

// ---------------------------- main attention kernel ----------------------------
// Phase 0: coalesced mask burst -> 64 bits/lane in registers (af-aligned).
// Phase 1: fused QK^T -> exp -> shfl -> reg-mask -> rsum + PV MFMAs.
// Pass B:  attn = AF * rinv streaming stores. Mask never touched in the chain.
template <bool WS>
__global__ __launch_bounds__(NTHREADS, 4)
void sdpa_main(const float* __restrict__ q, const float* __restrict__ k,
               const float* __restrict__ v, const int* __restrict__ mask,
               const unsigned short* __restrict__ Qb,
               const unsigned short* __restrict__ Kb,
               const unsigned short* __restrict__ Vb,
               float* __restrict__ ctx, float* __restrict__ attn)
{
    __shared__ float rowsum[ROWS];
    __shared__ float ctxlds[ROWS * DK];

    const int bid  = blockIdx.x;
    const int bh   = bid & (N_BH - 1);         // head-minor: head -> fixed XCD, K/V L2-resident
    const int qt   = bid >> 5;
    const int tid  = threadIdx.x;
    const int wave = tid >> 6;
    const int lane = tid & 63;
    const int m    = lane & 15;
    const int g    = lane >> 4;
    const long rowbase = (long)bh * S_LEN + qt * ROWS;
    const int tw   = wave << 8;                // this wave's 256-col slice

    if (tid < ROWS) rowsum[tid] = 0.0f;
    for (int i = tid; i < ROWS * DK; i += NTHREADS) ctxlds[i] = 0.0f;
    __syncthreads();

    // ---- Phase 0a: mask burst (16 coalesced 1KB loads/wave, independent) ----
    unsigned long long mbits = 0ull;           // nibble r = rows 0..15, cols tw+4*lane..+3
    {
        const int* mbase = mask + rowbase * S_LEN + tw + 4 * lane;
        #pragma unroll
        for (int r = 0; r < 16; ++r) {
            const i32x4 mk = __builtin_nontemporal_load((const i32x4*)(mbase + (long)r * S_LEN));
            const unsigned nib = (mk.x ? 1u : 0u) | (mk.y ? 2u : 0u)
                               | (mk.z ? 4u : 0u) | (mk.w ? 8u : 0u);
            mbits |= ((unsigned long long)nib) << (r * 4);
        }
    }

    // Q fragment (B operand): Q[col=m][k = ks*32 + g*8 + j]
    bf16x8 qfrag[2];
    if (WS) {
        const unsigned short* qp = Qb + (rowbase + m) * DK;
        qfrag[0] = *(const bf16x8*)(qp + g * 8);
        qfrag[1] = *(const bf16x8*)(qp + 32 + g * 8);
    } else {
        const float* qp = q + (rowbase + m) * DK;
        #pragma unroll
        for (int ks = 0; ks < 2; ++ks) {
            const float* p = qp + ks * 32 + g * 8;
            f32x4 x0 = *(const f32x4*)p, x1 = *(const f32x4*)(p + 4);
            qfrag[ks][0]=(short)f2bf(x0.x); qfrag[ks][1]=(short)f2bf(x0.y);
            qfrag[ks][2]=(short)f2bf(x0.z); qfrag[ks][3]=(short)f2bf(x0.w);
            qfrag[ks][4]=(short)f2bf(x1.x); qfrag[ks][5]=(short)f2bf(x1.y);
            qfrag[ks][6]=(short)f2bf(x1.z); qfrag[ks][7]=(short)f2bf(x1.w);
        }
    }

    // ---- Phase 0b: redistribute bits -> lane (m,g): byte kt = row m, cols tb..tb+7 ----
    unsigned long long lanemask = 0ull;
    {
        const unsigned mlo = (unsigned)mbits, mhi = (unsigned)(mbits >> 32);
        #pragma unroll
        for (int kt = 0; kt < 8; ++kt) {
            const int sA = kt * 8 + g * 2, sB = sA + 1;
            const unsigned aLo = (unsigned)__shfl((int)mlo, sA);
            const unsigned aHi = (unsigned)__shfl((int)mhi, sA);
            const unsigned bLo = (unsigned)__shfl((int)mlo, sB);
            const unsigned bHi = (unsigned)__shfl((int)mhi, sB);
            const unsigned long long A = ((unsigned long long)aHi << 32) | aLo;
            const unsigned long long B = ((unsigned long long)bHi << 32) | bLo;
            const unsigned byt = (unsigned)((A >> (4 * m)) & 0xFull)
                               | ((unsigned)((B >> (4 * m)) & 0xFull) << 4);
            lanemask |= ((unsigned long long)byt) << (8 * kt);
        }
    }

    const int srcA = ((g & 1) << 5) + m;
    const int srcB = srcA + 16;
    const int hi   = g >> 1;

    u32x4 AF[8];                               // masked e, af layout (row m, 8 cols)
    f32x4 cacc0 = {0,0,0,0}, cacc1 = {0,0,0,0}, cacc2 = {0,0,0,0}, cacc3 = {0,0,0,0};
    float rsum = 0.0f;

    #pragma unroll
    for (int kt = 0; kt < 8; ++kt) {
        // ---- QK^T for ct = 2kt (even) and 2kt+1 (odd) ----
        unsigned pk0e, pk1e, pk0o, pk1o;
        #pragma unroll
        for (int h = 0; h < 2; ++h) {
            const int t0 = tw + ((2 * kt + h) << 4);
            const int tk = t0 + m;             // A operand: K row (t dim)
            f32x4 acc = {0.f, 0.f, 0.f, 0.f};
            #pragma unroll
            for (int ks = 0; ks < 2; ++ks) {
                bf16x8 kfrag;
                if (WS) {
                    kfrag = *(const bf16x8*)(Kb + ((long)bh * S_LEN + tk) * DK + ks * 32 + g * 8);
                } else {
                    const float* kp = k + (long)bh * DK * S_LEN + (long)(ks * 32 + g * 8) * S_LEN + tk;
                    #pragma unroll
                    for (int j = 0; j < 8; ++j) kfrag[j] = (short)f2bf(kp[(long)j * S_LEN]);
                }
                acc = __builtin_amdgcn_mfma_f32_16x16x32_bf16(kfrag, qfrag[ks], acc, 0, 0, 0);
            }
            const float e0 = __expf(acc[0] * 0.125f);
            const float e1 = __expf(acc[1] * 0.125f);
            const float e2 = __expf(acc[2] * 0.125f);
            const float e3 = __expf(acc[3] * 0.125f);
            if (h == 0) { pk0e = pack_bf2(e0, e1); pk1e = pack_bf2(e2, e3); }
            else        { pk0o = pack_bf2(e0, e1); pk1o = pack_bf2(e2, e3); }
        }
        // ---- shfl: af = P[row m][cols tb..tb+7], tb = tw + kt*32 + g*8 ----
        const unsigned a0e = (unsigned)__shfl((int)pk0e, srcA);
        const unsigned a0o = (unsigned)__shfl((int)pk0o, srcA);
        const unsigned a1e = (unsigned)__shfl((int)pk1e, srcA);
        const unsigned a1o = (unsigned)__shfl((int)pk1o, srcA);
        const unsigned a2e = (unsigned)__shfl((int)pk0e, srcB);
        const unsigned a2o = (unsigned)__shfl((int)pk0o, srcB);
        const unsigned a3e = (unsigned)__shfl((int)pk1e, srcB);
        const unsigned a3o = (unsigned)__shfl((int)pk1o, srcB);
        u32x4 wv = { hi ? a0o : a0e, hi ? a1o : a1e,
                     hi ? a2o : a2e, hi ? a3o : a3e };
        // ---- mask from registers (bit i of mb <-> col tb+i) ----
        const unsigned mb = (unsigned)(lanemask >> (8 * kt)) & 0xFFu;
        if (mb & 1u)   wv.x &= 0xFFFF0000u;
        if (mb & 2u)   wv.x &= 0x0000FFFFu;
        if (mb & 4u)   wv.y &= 0xFFFF0000u;
        if (mb & 8u)   wv.y &= 0x0000FFFFu;
        if (mb & 16u)  wv.z &= 0xFFFF0000u;
        if (mb & 32u)  wv.z &= 0x0000FFFFu;
        if (mb & 64u)  wv.w &= 0xFFFF0000u;
        if (mb & 128u) wv.w &= 0x0000FFFFu;
        AF[kt] = wv;
        rsum += ((bf2f((unsigned short)(wv.x & 0xFFFF)) + bf2f((unsigned short)(wv.x >> 16)))
               + (bf2f((unsigned short)(wv.y & 0xFFFF)) + bf2f((unsigned short)(wv.y >> 16))))
              + ((bf2f((unsigned short)(wv.z & 0xFFFF)) + bf2f((unsigned short)(wv.z >> 16)))
               + (bf2f((unsigned short)(wv.w & 0xFFFF)) + bf2f((unsigned short)(wv.w >> 16))));
        // ---- PV MFMAs: A = af (masked), B = V[col=dt*16+m][k=tb+j] ----
        const bf16x8 af = __builtin_bit_cast(bf16x8, wv);
        const int tb = tw + (kt << 5) + (g << 3);
        #pragma unroll
        for (int dt = 0; dt < 4; ++dt) {
            bf16x8 bfv;
            if (WS) {
                bfv = *(const bf16x8*)(Vb + ((long)bh * DK + dt * 16 + m) * S_LEN + tb);
            } else {
                const float* vp = v + ((long)bh * S_LEN + tb) * DK + dt * 16 + m;
                #pragma unroll
                for (int j = 0; j < 8; ++j) bfv[j] = (short)f2bf(vp[j * DK]);
            }
            if      (dt == 0) cacc0 = __builtin_amdgcn_mfma_f32_16x16x32_bf16(af, bfv, cacc0, 0, 0, 0);
            else if (dt == 1) cacc1 = __builtin_amdgcn_mfma_f32_16x16x32_bf16(af, bfv, cacc1, 0, 0, 0);
            else if (dt == 2) cacc2 = __builtin_amdgcn_mfma_f32_16x16x32_bf16(af, bfv, cacc2, 0, 0, 0);
            else              cacc3 = __builtin_amdgcn_mfma_f32_16x16x32_bf16(af, bfv, cacc3, 0, 0, 0);
        }
    }

    // ---- reductions: rowsum + ctx partials ----
    rsum += __shfl_xor(rsum, 16);
    rsum += __shfl_xor(rsum, 32);              // lanes sharing m agree
    if (lane < 16) atomicAdd(&rowsum[lane], rsum);
    #pragma unroll
    for (int i = 0; i < 4; ++i) {
        atomicAdd(&ctxlds[(4 * g + i) * DK +  0 + m], cacc0[i]);
        atomicAdd(&ctxlds[(4 * g + i) * DK + 16 + m], cacc1[i]);
        atomicAdd(&ctxlds[(4 * g + i) * DK + 32 + m], cacc2[i]);
        atomicAdd(&ctxlds[(4 * g + i) * DK + 48 + m], cacc3[i]);
    }
    __syncthreads();

    // ---- pass B: stream attn = AF * rinv (nontemporal, 32B/lane contiguous) ----
    {
        const float rinv = 1.0f / rowsum[m];
        float* aout = attn + (rowbase + m) * (long)S_LEN;
        #pragma unroll
        for (int kt = 0; kt < 8; ++kt) {
            const u32x4 wv = AF[kt];
            const int tb = tw + (kt << 5) + (g << 3);
            f32x4 o0 = { bf2f((unsigned short)(wv.x & 0xFFFF)) * rinv,
                         bf2f((unsigned short)(wv.x >> 16))    * rinv,
                         bf2f((unsigned short)(wv.y & 0xFFFF)) * rinv,
                         bf2f((unsigned short)(wv.y >> 16))    * rinv };
            f32x4 o1 = { bf2f((unsigned short)(wv.z & 0xFFFF)) * rinv,
                         bf2f((unsigned short)(wv.z >> 16))    * rinv,
                         bf2f((unsigned short)(wv.w & 0xFFFF)) * rinv,
                         bf2f((unsigned short)(wv.w >> 16))    * rinv };
            __builtin_nontemporal_store(o0, (f32x4*)(aout + tb));
            __builtin_nontemporal_store(o1, (f32x4*)(aout + tb + 4));
        }
    }

    // ---- ctx epilogue ----
    #pragma unroll
    for (int i = tid; i < ROWS * DK; i += NTHREADS) {
        const int rr = i >> 6, dd = i & 63;
        ctx[(rowbase + rr) * DK + dd] = ctxlds[i] / rowsum[rr];
    }
}

extern "C" void kernel_launch(void* const* d_in, const int* in_sizes, int n_in,
                              void* d_out, int out_size, void* d_ws, size_t ws_size,
                              hipStream_t stream)
{
    const float* q    = (const float*)d_in[0];
    const float* k    = (const float*)d_in[1];
    const float* v    = (const float*)d_in[2];
    const int*   mask = (const int*)d_in[3];

    float* ctx  = (float*)d_out;
    float* attn = ctx + (size_t)N_BH * S_LEN * DK;

    const size_t nel = (size_t)N_BH * S_LEN * DK;
    const bool use_ws = ws_size >= nel * 3 * sizeof(unsigned short);
    unsigned short* Qb = (unsigned short*)d_ws;
    unsigned short* Kb = Qb + nel;
    unsigned short* Vb = Kb + nel;

    const int nblocks = N_BH * (S_LEN / ROWS);                 // 4096

    if (use_ws) {
        prep_qcast<<<(int)(nel / (256 * 8)), 256, 0, stream>>>(q, Qb);
        prep_k<<<N_BH * (S_LEN / 64), 256, 0, stream>>>(k, Kb);
        prep_v<<<N_BH * (S_LEN / 64), 256, 0, stream>>>(v, Vb);
        sdpa_main<true><<<nblocks, NTHREADS, 0, stream>>>(q, k, v, mask, Qb, Kb, Vb, ctx, attn);
    } else {
        sdpa_main<false><<<nblocks, NTHREADS, 0, stream>>>(q, k, v, mask,
                                                           nullptr, nullptr, nullptr, ctx, attn);
    }
}

// Round 9
// 459.062 us; speedup vs baseline: 1.0876x; 1.0367x over previous
//
#include <hip/hip_runtime.h>

#define S_LEN    2048
#define DK       64
#define N_BH     32
#define ROWS     16
#define NTHREADS 512

typedef float          f32x4  __attribute__((ext_vector_type(4)));
typedef int            i32x4  __attribute__((ext_vector_type(4)));
typedef short          bf16x8 __attribute__((ext_vector_type(8)));
typedef unsigned short u16x8  __attribute__((ext_vector_type(8)));
typedef unsigned int   u32x4  __attribute__((ext_vector_type(4)));

__device__ __forceinline__ unsigned short f2bf(float f) {
    unsigned u = __builtin_bit_cast(unsigned, f);
    u += 0x7fffu + ((u >> 16) & 1u);
    return (unsigned short)(u >> 16);
}
__device__ __forceinline__ float bf2f(unsigned short h) {
    unsigned u = ((unsigned)h) << 16;
    return __builtin_bit_cast(float, u);
}
__device__ __forceinline__ unsigned pack_bf2(float a, float b) {
    return (unsigned)f2bf(a) | ((unsigned)f2bf(b) << 16);
}

// ---------------- prep kernels: fragment-ordered bf16 layouts in d_ws ----------------
// Q2[((bh*128+qt)*2+ks)*512 + lane*8 + j] = q[bh][qt*16+m][ks*32+g*8+j], lane=g*16+m
__global__ void prep_q(const float* __restrict__ q, unsigned short* __restrict__ Q2) {
    const int bq = blockIdx.x;                 // bh*128 + qt
    const int tx = threadIdx.x;                // 128 threads: ks(1)|g(2)|m(4)
    const int ks = tx >> 6, g = (tx >> 4) & 3, m = tx & 15;
    const long row = ((long)(bq >> 7) * S_LEN + (bq & 127) * 16 + m);
    const float* p = q + row * DK + ks * 32 + g * 8;
    f32x4 x0 = *(const f32x4*)p, x1 = *(const f32x4*)(p + 4);
    u16x8 o;
    o[0]=f2bf(x0.x); o[1]=f2bf(x0.y); o[2]=f2bf(x0.z); o[3]=f2bf(x0.w);
    o[4]=f2bf(x1.x); o[5]=f2bf(x1.y); o[6]=f2bf(x1.z); o[7]=f2bf(x1.w);
    *(u16x8*)(Q2 + (long)bq * 1024 + tx * 8) = o;
}

// K2[((((bh*128+t16)*2+ks)*4+g)*16+m)*8 + j] = k[bh][d=ks*32+g*8+j][t=t16*16+m]
__global__ void prep_k(const float* __restrict__ k, unsigned short* __restrict__ K2) {
    __shared__ float t[64][65];
    const int bh = blockIdx.x >> 5, s0 = (blockIdx.x & 31) << 6;
    const int tx = threadIdx.x;
    const float* kb = k + (long)bh * DK * S_LEN;
    #pragma unroll
    for (int i = 0; i < 16; ++i) {
        const int d = (i << 2) + (tx >> 6), s = tx & 63;
        t[d][s] = kb[(long)d * S_LEN + s0 + s];
    }
    __syncthreads();
    #pragma unroll
    for (int it = 0; it < 2; ++it) {
        const int flat = it * 256 + tx;        // m(4)|g(2)|ks(1)|t16g(2)
        const int m = flat & 15, g = (flat >> 4) & 3, ks = (flat >> 6) & 1, t16g = flat >> 7;
        const int sl = t16g * 16 + m;
        const int d0 = ks * 32 + g * 8;
        u16x8 o;
        #pragma unroll
        for (int j = 0; j < 8; ++j) o[j] = f2bf(t[d0 + j][sl]);
        const long idx = ((((long)(bh * 128 + (s0 >> 4) + t16g) * 2 + ks) * 4 + g) * 16 + m) * 8;
        *(u16x8*)(K2 + idx) = o;
    }
}

// V2[((bh*256+tbi)*64+d)*8 + j] = v[bh][t=tbi*8+j][d]
__global__ void prep_v(const float* __restrict__ v, unsigned short* __restrict__ V2) {
    __shared__ float t[64][65];
    const int bh = blockIdx.x >> 5, s0 = (blockIdx.x & 31) << 6;
    const int tx = threadIdx.x;
    #pragma unroll
    for (int i = 0; i < 16; ++i) {
        const int s = (i << 2) + (tx >> 6), d = tx & 63;
        t[s][d] = v[((long)bh * S_LEN + s0 + s) * DK + d];
    }
    __syncthreads();
    #pragma unroll
    for (int it = 0; it < 2; ++it) {
        const int flat = it * 256 + tx;        // d(6)|tbl(3)
        const int d = flat & 63, tbl = flat >> 6;
        u16x8 o;
        #pragma unroll
        for (int j = 0; j < 8; ++j) o[j] = f2bf(t[tbl * 8 + j][d]);
        const long idx = (((long)(bh * 256 + (s0 >> 3) + tbl) * 64) + d) * 8;
        *(u16x8*)(V2 + idx) = o;
    }
}

// ---------------------------- main attention kernel ----------------------------
// Phase 0: coalesced mask burst -> 64 bits/lane in registers (af-aligned).
// Phase 1: fused QK^T -> exp -> shfl -> reg-mask -> rsum + PV MFMAs.
// All K/V/Q loads fully coalesced from fragment-ordered ws. Pass B streams attn.
template <bool WS>
__global__ __launch_bounds__(NTHREADS, 4)
void sdpa_main(const float* __restrict__ q, const float* __restrict__ k,
               const float* __restrict__ v, const int* __restrict__ mask,
               const unsigned short* __restrict__ Q2,
               const unsigned short* __restrict__ K2,
               const unsigned short* __restrict__ V2,
               float* __restrict__ ctx, float* __restrict__ attn)
{
    __shared__ float rowsum[ROWS];
    __shared__ float ctxlds[ROWS * DK];

    const int bid  = blockIdx.x;
    const int bh   = bid & (N_BH - 1);         // head-minor: head -> fixed XCD, K/V L2-resident
    const int qt   = bid >> 5;
    const int tid  = threadIdx.x;
    const int wave = tid >> 6;
    const int lane = tid & 63;
    const int m    = lane & 15;
    const int g    = lane >> 4;
    const long rowbase = (long)bh * S_LEN + qt * ROWS;
    const int tw   = wave << 8;                // this wave's 256-col slice

    if (tid < ROWS) rowsum[tid] = 0.0f;
    for (int i = tid; i < ROWS * DK; i += NTHREADS) ctxlds[i] = 0.0f;
    __syncthreads();

    // ---- Phase 0a: mask burst (16 coalesced 1KB loads/wave, independent) ----
    unsigned long long mbits = 0ull;           // nibble r = rows 0..15, cols tw+4*lane..+3
    {
        const int* mbase = mask + rowbase * S_LEN + tw + 4 * lane;
        #pragma unroll
        for (int r = 0; r < 16; ++r) {
            const i32x4 mk = __builtin_nontemporal_load((const i32x4*)(mbase + (long)r * S_LEN));
            const unsigned nib = (mk.x ? 1u : 0u) | (mk.y ? 2u : 0u)
                               | (mk.z ? 4u : 0u) | (mk.w ? 8u : 0u);
            mbits |= ((unsigned long long)nib) << (r * 4);
        }
    }

    // Q fragment (B operand): Q[col=m][k = ks*32 + g*8 + j]
    bf16x8 qfrag[2];
    if (WS) {
        const unsigned short* qp = Q2 + ((long)((bh * 128 + qt) * 2) << 9) + (lane << 3);
        qfrag[0] = *(const bf16x8*)qp;
        qfrag[1] = *(const bf16x8*)(qp + 512);
    } else {
        const float* qp = q + (rowbase + m) * DK;
        #pragma unroll
        for (int ks = 0; ks < 2; ++ks) {
            const float* p = qp + ks * 32 + g * 8;
            f32x4 x0 = *(const f32x4*)p, x1 = *(const f32x4*)(p + 4);
            qfrag[ks][0]=(short)f2bf(x0.x); qfrag[ks][1]=(short)f2bf(x0.y);
            qfrag[ks][2]=(short)f2bf(x0.z); qfrag[ks][3]=(short)f2bf(x0.w);
            qfrag[ks][4]=(short)f2bf(x1.x); qfrag[ks][5]=(short)f2bf(x1.y);
            qfrag[ks][6]=(short)f2bf(x1.z); qfrag[ks][7]=(short)f2bf(x1.w);
        }
    }

    // ---- Phase 0b: redistribute bits -> lane (m,g): byte kt = row m, cols tb..tb+7 ----
    unsigned long long lanemask = 0ull;
    {
        const unsigned mlo = (unsigned)mbits, mhi = (unsigned)(mbits >> 32);
        #pragma unroll
        for (int kt = 0; kt < 8; ++kt) {
            const int sA = kt * 8 + g * 2, sB = sA + 1;
            const unsigned aLo = (unsigned)__shfl((int)mlo, sA);
            const unsigned aHi = (unsigned)__shfl((int)mhi, sA);
            const unsigned bLo = (unsigned)__shfl((int)mlo, sB);
            const unsigned bHi = (unsigned)__shfl((int)mhi, sB);
            const unsigned long long A = ((unsigned long long)aHi << 32) | aLo;
            const unsigned long long B = ((unsigned long long)bHi << 32) | bLo;
            const unsigned byt = (unsigned)((A >> (4 * m)) & 0xFull)
                               | ((unsigned)((B >> (4 * m)) & 0xFull) << 4);
            lanemask |= ((unsigned long long)byt) << (8 * kt);
        }
    }

    const int srcA = ((g & 1) << 5) + m;
    const int srcB = srcA + 16;
    const int hi   = g >> 1;

    u32x4 AF[8];                               // masked e, af layout (row m, 8 cols)
    f32x4 cacc0 = {0,0,0,0}, cacc1 = {0,0,0,0}, cacc2 = {0,0,0,0}, cacc3 = {0,0,0,0};
    float rsum = 0.0f;

    #pragma unroll
    for (int kt = 0; kt < 8; ++kt) {
        // ---- QK^T for ct = 2kt (even) and 2kt+1 (odd) ----
        unsigned pk0e, pk1e, pk0o, pk1o;
        #pragma unroll
        for (int h = 0; h < 2; ++h) {
            f32x4 acc = {0.f, 0.f, 0.f, 0.f};
            #pragma unroll
            for (int ks = 0; ks < 2; ++ks) {
                bf16x8 kfrag;
                if (WS) {
                    // fully-coalesced: base + lane*16B
                    const unsigned short* kp = K2
                        + (((long)(bh * 128 + wave * 16 + 2 * kt + h) * 2 + ks) << 9)
                        + (lane << 3);
                    kfrag = *(const bf16x8*)kp;
                } else {
                    const int t0 = tw + ((2 * kt + h) << 4);
                    const int tk = t0 + m;
                    const float* kp = k + (long)bh * DK * S_LEN + (long)(ks * 32 + g * 8) * S_LEN + tk;
                    #pragma unroll
                    for (int j = 0; j < 8; ++j) kfrag[j] = (short)f2bf(kp[(long)j * S_LEN]);
                }
                acc = __builtin_amdgcn_mfma_f32_16x16x32_bf16(kfrag, qfrag[ks], acc, 0, 0, 0);
            }
            const float e0 = __expf(acc[0] * 0.125f);
            const float e1 = __expf(acc[1] * 0.125f);
            const float e2 = __expf(acc[2] * 0.125f);
            const float e3 = __expf(acc[3] * 0.125f);
            if (h == 0) { pk0e = pack_bf2(e0, e1); pk1e = pack_bf2(e2, e3); }
            else        { pk0o = pack_bf2(e0, e1); pk1o = pack_bf2(e2, e3); }
        }
        // ---- shfl: af = P[row m][cols tb..tb+7], tb = tw + kt*32 + g*8 ----
        const unsigned a0e = (unsigned)__shfl((int)pk0e, srcA);
        const unsigned a0o = (unsigned)__shfl((int)pk0o, srcA);
        const unsigned a1e = (unsigned)__shfl((int)pk1e, srcA);
        const unsigned a1o = (unsigned)__shfl((int)pk1o, srcA);
        const unsigned a2e = (unsigned)__shfl((int)pk0e, srcB);
        const unsigned a2o = (unsigned)__shfl((int)pk0o, srcB);
        const unsigned a3e = (unsigned)__shfl((int)pk1e, srcB);
        const unsigned a3o = (unsigned)__shfl((int)pk1o, srcB);
        u32x4 wv = { hi ? a0o : a0e, hi ? a1o : a1e,
                     hi ? a2o : a2e, hi ? a3o : a3e };
        // ---- mask from registers (bit i of mb <-> col tb+i) ----
        const unsigned mb = (unsigned)(lanemask >> (8 * kt)) & 0xFFu;
        if (mb & 1u)   wv.x &= 0xFFFF0000u;
        if (mb & 2u)   wv.x &= 0x0000FFFFu;
        if (mb & 4u)   wv.y &= 0xFFFF0000u;
        if (mb & 8u)   wv.y &= 0x0000FFFFu;
        if (mb & 16u)  wv.z &= 0xFFFF0000u;
        if (mb & 32u)  wv.z &= 0x0000FFFFu;
        if (mb & 64u)  wv.w &= 0xFFFF0000u;
        if (mb & 128u) wv.w &= 0x0000FFFFu;
        AF[kt] = wv;
        rsum += ((bf2f((unsigned short)(wv.x & 0xFFFF)) + bf2f((unsigned short)(wv.x >> 16)))
               + (bf2f((unsigned short)(wv.y & 0xFFFF)) + bf2f((unsigned short)(wv.y >> 16))))
              + ((bf2f((unsigned short)(wv.z & 0xFFFF)) + bf2f((unsigned short)(wv.z >> 16)))
               + (bf2f((unsigned short)(wv.w & 0xFFFF)) + bf2f((unsigned short)(wv.w >> 16))));
        // ---- PV MFMAs: A = af (masked), B = V[col=dt*16+m][k=tb+j] ----
        const bf16x8 af = __builtin_bit_cast(bf16x8, wv);
        #pragma unroll
        for (int dt = 0; dt < 4; ++dt) {
            bf16x8 bfv;
            if (WS) {
                // 4 x 256B segments: tbi = wave*32 + kt*4 + g
                const unsigned short* vp2 = V2
                    + ((((long)(bh * 256 + (wave << 5) + (kt << 2) + g)) << 6) + dt * 16 + m) * 8;
                bfv = *(const bf16x8*)vp2;
            } else {
                const int tb = tw + (kt << 5) + (g << 3);
                const float* vp = v + ((long)bh * S_LEN + tb) * DK + dt * 16 + m;
                #pragma unroll
                for (int j = 0; j < 8; ++j) bfv[j] = (short)f2bf(vp[j * DK]);
            }
            if      (dt == 0) cacc0 = __builtin_amdgcn_mfma_f32_16x16x32_bf16(af, bfv, cacc0, 0, 0, 0);
            else if (dt == 1) cacc1 = __builtin_amdgcn_mfma_f32_16x16x32_bf16(af, bfv, cacc1, 0, 0, 0);
            else if (dt == 2) cacc2 = __builtin_amdgcn_mfma_f32_16x16x32_bf16(af, bfv, cacc2, 0, 0, 0);
            else              cacc3 = __builtin_amdgcn_mfma_f32_16x16x32_bf16(af, bfv, cacc3, 0, 0, 0);
        }
    }

    // ---- reductions: rowsum + ctx partials ----
    rsum += __shfl_xor(rsum, 16);
    rsum += __shfl_xor(rsum, 32);              // lanes sharing m agree
    if (lane < 16) atomicAdd(&rowsum[lane], rsum);
    #pragma unroll
    for (int i = 0; i < 4; ++i) {
        atomicAdd(&ctxlds[(4 * g + i) * DK +  0 + m], cacc0[i]);
        atomicAdd(&ctxlds[(4 * g + i) * DK + 16 + m], cacc1[i]);
        atomicAdd(&ctxlds[(4 * g + i) * DK + 32 + m], cacc2[i]);
        atomicAdd(&ctxlds[(4 * g + i) * DK + 48 + m], cacc3[i]);
    }
    __syncthreads();

    // ---- pass B: stream attn = AF * rinv (nontemporal, 32B/lane contiguous) ----
    {
        const float rinv = 1.0f / rowsum[m];
        float* aout = attn + (rowbase + m) * (long)S_LEN;
        #pragma unroll
        for (int kt = 0; kt < 8; ++kt) {
            const u32x4 wv = AF[kt];
            const int tb = tw + (kt << 5) + (g << 3);
            f32x4 o0 = { bf2f((unsigned short)(wv.x & 0xFFFF)) * rinv,
                         bf2f((unsigned short)(wv.x >> 16))    * rinv,
                         bf2f((unsigned short)(wv.y & 0xFFFF)) * rinv,
                         bf2f((unsigned short)(wv.y >> 16))    * rinv };
            f32x4 o1 = { bf2f((unsigned short)(wv.z & 0xFFFF)) * rinv,
                         bf2f((unsigned short)(wv.z >> 16))    * rinv,
                         bf2f((unsigned short)(wv.w & 0xFFFF)) * rinv,
                         bf2f((unsigned short)(wv.w >> 16))    * rinv };
            __builtin_nontemporal_store(o0, (f32x4*)(aout + tb));
            __builtin_nontemporal_store(o1, (f32x4*)(aout + tb + 4));
        }
    }

    // ---- ctx epilogue ----
    #pragma unroll
    for (int i = tid; i < ROWS * DK; i += NTHREADS) {
        const int rr = i >> 6, dd = i & 63;
        ctx[(rowbase + rr) * DK + dd] = ctxlds[i] / rowsum[rr];
    }
}

extern "C" void kernel_launch(void* const* d_in, const int* in_sizes, int n_in,
                              void* d_out, int out_size, void* d_ws, size_t ws_size,
                              hipStream_t stream)
{
    const float* q    = (const float*)d_in[0];
    const float* k    = (const float*)d_in[1];
    const float* v    = (const float*)d_in[2];
    const int*   mask = (const int*)d_in[3];

    float* ctx  = (float*)d_out;
    float* attn = ctx + (size_t)N_BH * S_LEN * DK;

    const size_t nel = (size_t)N_BH * S_LEN * DK;
    const bool use_ws = ws_size >= nel * 3 * sizeof(unsigned short);
    unsigned short* Q2 = (unsigned short*)d_ws;
    unsigned short* K2 = Q2 + nel;
    unsigned short* V2 = K2 + nel;

    const int nblocks = N_BH * (S_LEN / ROWS);                 // 4096

    if (use_ws) {
        prep_q<<<N_BH * 128, 128, 0, stream>>>(q, Q2);
        prep_k<<<N_BH * (S_LEN / 64), 256, 0, stream>>>(k, K2);
        prep_v<<<N_BH * (S_LEN / 64), 256, 0, stream>>>(v, V2);
        sdpa_main<true><<<nblocks, NTHREADS, 0, stream>>>(q, k, v, mask, Q2, K2, V2, ctx, attn);
    } else {
        sdpa_main<false><<<nblocks, NTHREADS, 0, stream>>>(q, k, v, mask,
                                                           nullptr, nullptr, nullptr, ctx, attn);
    }
}